// Round 1
// baseline (1717.333 us; speedup 1.0000x reference)
//
#include <hip/hip_runtime.h>
#include <math.h>

#define DD 33
#define TT 49
#define HH 64
#define QQ 64
#define NB 33
#define NT 256

// ws layout (float offsets)
#define O_WIHT   0        // 33*192  = 6336   gru_wih^T
#define O_WHHT   6336     // 64*192  = 12288  gru_whh^T
#define O_WU0T   18624    // 64*64   = 4096   wu0_w^T
#define O_WU1T   22720    // 128*64  = 8192   wu1_w^T
#define O_WUT    30912    // 192*64  = 12288  wu_w^T
#define O_GH     43200    // 49*64   = 3136   gamma_h[t][i]
#define O_GS     46336    // 49*64   = 3136   gamma_st[t][i]
#define O_XC     49472    // 49*33   = 1617   published x_st_c
#define O_R      51089    // 49*66   = 3234   published r1(33), r2(33)
#define CTR_OFF  54324    // unsigned counters[TT+1]
#define PREP_N   49472

__device__ __forceinline__ float sigm(float x) { return 1.f / (1.f + expf(-x)); }

__device__ __forceinline__ float rsum64(float v) {
#pragma unroll
  for (int o = 32; o > 0; o >>= 1) v += __shfl_xor(v, o, 64);
  return v;
}
__device__ __forceinline__ float rmax64(float v) {
#pragma unroll
  for (int o = 32; o > 0; o >>= 1) v = fmaxf(v, __shfl_xor(v, o, 64));
  return v;
}

__device__ __forceinline__ void gbar(unsigned* c) {
  __syncthreads();
  if (threadIdx.x == 0) {
    __hip_atomic_fetch_add(c, 1u, __ATOMIC_RELEASE, __HIP_MEMORY_SCOPE_AGENT);
    while (__hip_atomic_load(c, __ATOMIC_ACQUIRE, __HIP_MEMORY_SCOPE_AGENT) < NB) {
      __builtin_amdgcn_s_sleep(2);
    }
  }
  __syncthreads();
}

extern "C" __global__ void gmgru_prep(
    const float* __restrict__ data, const float* __restrict__ gh_w,
    const float* __restrict__ gh_b, const float* __restrict__ gst_w,
    const float* __restrict__ gst_b, const float* __restrict__ wih,
    const float* __restrict__ whh, const float* __restrict__ wu0,
    const float* __restrict__ wu1, const float* __restrict__ wu,
    float* __restrict__ ws) {
  int idx = blockIdx.x * blockDim.x + threadIdx.x;
  if (idx < 6336) {                       // wihT[k*192+j] = wih[j*33+k]
    int k = idx / 192, j = idx % 192;
    ws[O_WIHT + idx] = wih[j * DD + k];
  } else if (idx < 18624) {               // whhT[k*192+j] = whh[j*64+k]
    int r = idx - 6336; int k = r / 192, j = r % 192;
    ws[O_WHHT + r] = whh[j * HH + k];
  } else if (idx < 22720) {               // wu0T[k*64+q] = wu0[q*64+k]
    int r = idx - 18624; int k = r / 64, q = r % 64;
    ws[O_WU0T + r] = wu0[q * HH + k];
  } else if (idx < 30912) {               // wu1T[k*64+q] = wu1[q*128+k]
    int r = idx - 22720; int k = r / 64, q = r % 64;
    ws[O_WU1T + r] = wu1[q * 128 + k];
  } else if (idx < 43200) {               // wuT[k*64+q] = wu[q*192+k]
    int r = idx - 30912; int k = r / 64, q = r % 64;
    ws[O_WUT + r] = wu[q * 192 + k];
  } else if (idx < 46336) {               // gamma_h[t][i]
    int r = idx - 43200; int t = r / 64, i = r % 64;
    float s = gh_b[i];
    for (int d2 = 0; d2 < DD; ++d2)
      s += data[2 * DD * TT + d2 * TT + t] * gh_w[i * DD + d2];
    ws[O_GH + r] = expf(-fmaxf(s, 0.f));
  } else if (idx < PREP_N) {              // gamma_st[t][i]
    int r = idx - 46336; int t = r / 64, i = r % 64;
    float s = gst_b[i];
    for (int d2 = 0; d2 < DD; ++d2)
      s += data[2 * DD * TT + d2 * TT + t] * gst_w[i * DD + d2];
    ws[O_GS + r] = expf(-fmaxf(s, 0.f));
  }
}

extern "C" __global__ void __launch_bounds__(NT)
gmgru_main(const float* __restrict__ data, const float* __restrict__ h0,
           const float* __restrict__ H0, const float* __restrict__ bih,
           const float* __restrict__ bhh, const float* __restrict__ wu0b,
           const float* __restrict__ wu1b, const float* __restrict__ wub,
           const float* __restrict__ wh_w, const float* __restrict__ wh_b,
           const float* __restrict__ xst_w, const float* __restrict__ xst_b,
           const float* __restrict__ wrg_w, const float* __restrict__ wrs,
           const float* __restrict__ tWz, const float* __restrict__ tUzx,
           const float* __restrict__ tUzh, const float* __restrict__ tWr,
           const float* __restrict__ tUrx, const float* __restrict__ tUrh,
           const float* __restrict__ tWh, const float* __restrict__ tUhx,
           const float* __restrict__ tUhh, const float* __restrict__ tbz,
           const float* __restrict__ tbr, const float* __restrict__ tbh,
           float* __restrict__ ws, unsigned* __restrict__ ctr,
           float* __restrict__ out) {
  // LDS: tensor weights (transposed, float4-friendly) + small state
  __shared__ __attribute__((aligned(16))) float wbuf[6][4096];  // 96 KB
  __shared__ float ux[3][HH], tb[3][HH];
  __shared__ float Hrow[HH], Hdec[HH], hpre[HH], hprev[HH], hnew[HH], h0s[HH];
  __shared__ float hist[3][HH];
  __shared__ float xcs[DD];
  __shared__ float giL[3 * HH], ghL[3 * HH];
  __shared__ float uvec[QQ];
  __shared__ float part[4][4][HH];
  __shared__ float scal[4];  // 0:x_st(t)  2:prev_xgt  3:prev_xst

  const int tid = threadIdx.x;
  const int dd = blockIdx.x;
  const int wid = tid >> 6;
  const int lane = tid & 63;

  // ---- one-time staging: 6 tensor matrices row dd -> LDS (transposed) ----
  {
    const float* srcs[6] = {tWz, tUzh, tWr, tUrh, tWh, tUhh};
#pragma unroll
    for (int m = 0; m < 6; ++m) {
      const float* s = srcs[m] + dd * 4096;
#pragma unroll
      for (int c = 0; c < 4; ++c) {
        int f = tid * 16 + c * 4;                 // source flat idx (i*64+k)
        float4 v = *reinterpret_cast<const float4*>(s + f);
        int i = f >> 6, k = f & 63;
        *reinterpret_cast<float4*>(&wbuf[m][(k >> 2) * 256 + i * 4]) = v;
      }
    }
  }
  if (tid < HH) {
    ux[0][tid] = tUzx[dd * HH + tid];
    ux[1][tid] = tUrx[dd * HH + tid];
    ux[2][tid] = tUhx[dd * HH + tid];
    tb[0][tid] = tbz[tid];
    tb[1][tid] = tbr[tid];
    tb[2][tid] = tbh[tid];
    Hrow[tid] = H0[dd * HH + tid];
    float h0v = h0[tid];
    h0s[tid] = h0v;
    hprev[tid] = h0v;
  }
  __syncthreads();

  for (int t = 0; t < TT; ++t) {
    // ---- pre-barrier: x_st from own H-row; publish x_st_c[dd] ----
    if (wid == 0) {
      float v = Hrow[lane] * xst_w[lane];
      float s = rsum64(v);
      if (lane == 0) {
        float xstv = s + xst_b[0];
        float xv = data[dd * TT + t];
        float mv = data[DD * TT + dd * TT + t];
        float xcv = mv * xv + (1.f - mv) * xstv;
        scal[0] = xstv;
        __hip_atomic_store(&ws[O_XC + t * DD + dd], xcv, __ATOMIC_RELAXED,
                           __HIP_MEMORY_SCOPE_AGENT);
      }
    }
    gbar(&ctr[t]);

    // ---- P1: gather x_st_c; decay h,H; finish softmax of step t-1 ----
    if (tid < DD)
      xcs[tid] = __hip_atomic_load(&ws[O_XC + t * DD + tid], __ATOMIC_RELAXED,
                                   __HIP_MEMORY_SCOPE_AGENT);
    if (tid < HH) {
      Hdec[tid] = ws[O_GS + t * HH + tid] * Hrow[tid];
      hpre[tid] = ws[O_GH + t * HH + tid] * hprev[tid];
    }
    if (wid == 1 && t > 0) {
      float r1v = -INFINITY, r2v = -INFINITY;
      if (lane < DD) {
        r1v = __hip_atomic_load(&ws[O_R + (t - 1) * 66 + lane],
                                __ATOMIC_RELAXED, __HIP_MEMORY_SCOPE_AGENT);
        r2v = __hip_atomic_load(&ws[O_R + (t - 1) * 66 + 33 + lane],
                                __ATOMIC_RELAXED, __HIP_MEMORY_SCOPE_AGENT);
      }
      float m1 = rmax64(r1v), m2 = rmax64(r2v);
      float e1 = (lane < DD) ? expf(r1v - m1) : 0.f;
      float e2 = (lane < DD) ? expf(r2v - m2) : 0.f;
      float s1 = rsum64(e1), s2 = rsum64(e2);
      float r1o = __shfl(r1v, dd, 64);
      float r2o = __shfl(r2v, dd, 64);
      if (lane == 0) {
        float a1 = expf(r1o - m1) / s1;
        float a2 = expf(r2o - m2) / s2;
        out[TT * DD * HH + dd * TT + (t - 1)] = a1 * scal[2] + a2 * scal[3];
      }
    }
    __syncthreads();

    // ---- P2: GRU cell matvecs (redundant in every block) ----
    if (tid < 3 * HH) {
      float gi = bih[tid];
      for (int k = 0; k < DD; ++k) gi += ws[O_WIHT + k * 192 + tid] * xcs[k];
      float gh = bhh[tid];
      for (int k = 0; k < HH; ++k) gh += ws[O_WHHT + k * 192 + tid] * hpre[k];
      giL[tid] = gi;
      ghL[tid] = gh;
    }
    __syncthreads();

    // ---- P3: gates -> h_t ----
    if (tid < HH) {
      float r = sigm(giL[tid] + ghL[tid]);
      float z = sigm(giL[HH + tid] + ghL[HH + tid]);
      float n = tanhf(giL[2 * HH + tid] + r * ghL[2 * HH + tid]);
      hnew[tid] = (1.f - z) * n + z * hpre[tid];
    }
    __syncthreads();

    // ---- P4: tensor-GRU partial dots (4 waves x 16 k's each) ----
    {
      float Hv[16], hv[16];
#pragma unroll
      for (int j = 0; j < 16; ++j) {
        Hv[j] = Hdec[wid * 16 + j];
        hv[j] = hnew[wid * 16 + j];
      }
      float pz = 0.f, pr = 0.f, pwh = 0.f, puh = 0.f;
#pragma unroll
      for (int g = 0; g < 4; ++g) {
        const int kg = (wid * 4 + g) * 256 + lane * 4;
        float4 wz = *reinterpret_cast<const float4*>(&wbuf[0][kg]);
        float4 uz = *reinterpret_cast<const float4*>(&wbuf[1][kg]);
        float4 wr = *reinterpret_cast<const float4*>(&wbuf[2][kg]);
        float4 ur = *reinterpret_cast<const float4*>(&wbuf[3][kg]);
        float4 wh = *reinterpret_cast<const float4*>(&wbuf[4][kg]);
        float4 uh = *reinterpret_cast<const float4*>(&wbuf[5][kg]);
        const float a0 = Hv[g * 4 + 0], a1 = Hv[g * 4 + 1];
        const float a2 = Hv[g * 4 + 2], a3 = Hv[g * 4 + 3];
        const float b0 = hv[g * 4 + 0], b1 = hv[g * 4 + 1];
        const float b2 = hv[g * 4 + 2], b3 = hv[g * 4 + 3];
        pz += wz.x * a0 + wz.y * a1 + wz.z * a2 + wz.w * a3;
        pz += uz.x * b0 + uz.y * b1 + uz.z * b2 + uz.w * b3;
        pr += wr.x * a0 + wr.y * a1 + wr.z * a2 + wr.w * a3;
        pr += ur.x * b0 + ur.y * b1 + ur.z * b2 + ur.w * b3;
        pwh += wh.x * a0 + wh.y * a1 + wh.z * a2 + wh.w * a3;
        puh += uh.x * b0 + uh.y * b1 + uh.z * b2 + uh.w * b3;
      }
      part[0][wid][lane] = pz;
      part[1][wid][lane] = pr;
      part[2][wid][lane] = pwh;
      part[3][wid][lane] = puh;
    }
    __syncthreads();

    // ---- P5: wave0 combines tensor gates -> H_t row; wave1 computes u_t ----
    if (wid == 0) {
      float sz = part[0][0][lane] + part[0][1][lane] + part[0][2][lane] + part[0][3][lane];
      float sr = part[1][0][lane] + part[1][1][lane] + part[1][2][lane] + part[1][3][lane];
      float swh = part[2][0][lane] + part[2][1][lane] + part[2][2][lane] + part[2][3][lane];
      float suh = part[3][0][lane] + part[3][1][lane] + part[3][2][lane] + part[3][3][lane];
      float xc = xcs[dd];
      float z = sigm(sz + ux[0][lane] * xc + tb[0][lane]);
      float r = sigm(sr + ux[1][lane] * xc + tb[1][lane]);
      float hh = tanhf(r * swh + ux[2][lane] * xc + suh + tb[2][lane]);
      float Hn = z * Hdec[lane] + (1.f - z) * hh;
      Hrow[lane] = Hn;
      out[t * DD * HH + dd * HH + lane] = Hn;
    } else if (wid == 1) {
      const int q = lane;
      float acc;
      if (t == 0) {
        acc = wu0b[q];
        for (int k = 0; k < HH; ++k) acc += ws[O_WU0T + k * 64 + q] * h0s[k];
      } else if (t == 1) {
        acc = wu1b[q];
        for (int k = 0; k < HH; ++k) acc += ws[O_WU1T + k * 64 + q] * h0s[k];
        for (int k = 0; k < HH; ++k) acc += ws[O_WU1T + (64 + k) * 64 + q] * hist[0][k];
      } else if (t == 2) {
        acc = wub[q];
        for (int k = 0; k < HH; ++k) acc += ws[O_WUT + k * 64 + q] * h0s[k];
        for (int k = 0; k < HH; ++k) acc += ws[O_WUT + (64 + k) * 64 + q] * hist[0][k];
        for (int k = 0; k < HH; ++k) acc += ws[O_WUT + (128 + k) * 64 + q] * hist[1][k];
      } else {
        acc = wub[q];
        const int s0 = (t - 3) % 3, s1 = (t - 2) % 3, s2 = (t - 1) % 3;
        for (int k = 0; k < HH; ++k) acc += ws[O_WUT + k * 64 + q] * hist[s0][k];
        for (int k = 0; k < HH; ++k) acc += ws[O_WUT + (64 + k) * 64 + q] * hist[s1][k];
        for (int k = 0; k < HH; ++k) acc += ws[O_WUT + (128 + k) * 64 + q] * hist[s2][k];
      }
      uvec[q] = acc;
    }
    __syncthreads();

    // ---- P6: x_gt_hat, a, b; publish softmax logits; roll state ----
    if (wid == 0) {
      float v1 = wh_w[dd * 128 + lane] * hnew[lane] +
                 wh_w[dd * 128 + 64 + lane] * uvec[lane];
      float xgt = rsum64(v1);
      float v2 = wrg_w[dd * HH + lane] * hnew[lane];
      float av = rsum64(v2);
      float v3 = wrs[lane] * Hrow[lane];
      float bv = rsum64(v3);
      hist[t % 3][lane] = hnew[lane];
      hprev[lane] = hnew[lane];
      if (lane == 0) {
        float s = av + bv;
        __hip_atomic_store(&ws[O_R + t * 66 + dd], av / s, __ATOMIC_RELAXED,
                           __HIP_MEMORY_SCOPE_AGENT);
        __hip_atomic_store(&ws[O_R + t * 66 + 33 + dd], bv / s,
                           __ATOMIC_RELAXED, __HIP_MEMORY_SCOPE_AGENT);
        scal[2] = xgt + wh_b[dd];
        scal[3] = scal[0];
      }
    }
    // next iteration's gbar() begins with __syncthreads()
  }

  // ---- epilogue: softmax for step TT-1 ----
  gbar(&ctr[TT]);
  if (wid == 1) {
    float r1v = -INFINITY, r2v = -INFINITY;
    if (lane < DD) {
      r1v = __hip_atomic_load(&ws[O_R + (TT - 1) * 66 + lane], __ATOMIC_RELAXED,
                              __HIP_MEMORY_SCOPE_AGENT);
      r2v = __hip_atomic_load(&ws[O_R + (TT - 1) * 66 + 33 + lane],
                              __ATOMIC_RELAXED, __HIP_MEMORY_SCOPE_AGENT);
    }
    float m1 = rmax64(r1v), m2 = rmax64(r2v);
    float e1 = (lane < DD) ? expf(r1v - m1) : 0.f;
    float e2 = (lane < DD) ? expf(r2v - m2) : 0.f;
    float s1 = rsum64(e1), s2 = rsum64(e2);
    float r1o = __shfl(r1v, dd, 64);
    float r2o = __shfl(r2v, dd, 64);
    if (lane == 0) {
      float a1 = expf(r1o - m1) / s1;
      float a2 = expf(r2o - m2) / s2;
      out[TT * DD * HH + dd * TT + (TT - 1)] = a1 * scal[2] + a2 * scal[3];
    }
  }
}

extern "C" void kernel_launch(void* const* d_in, const int* in_sizes, int n_in,
                              void* d_out, int out_size, void* d_ws,
                              size_t ws_size, hipStream_t stream) {
  (void)in_sizes; (void)n_in; (void)out_size; (void)ws_size;
  const float* data   = (const float*)d_in[0];
  const float* h0     = (const float*)d_in[1];
  const float* H0     = (const float*)d_in[2];
  const float* gh_w   = (const float*)d_in[3];
  const float* gh_b   = (const float*)d_in[4];
  const float* gst_w  = (const float*)d_in[5];
  const float* gst_b  = (const float*)d_in[6];
  const float* wih    = (const float*)d_in[7];
  const float* whh    = (const float*)d_in[8];
  const float* bih    = (const float*)d_in[9];
  const float* bhh    = (const float*)d_in[10];
  const float* wu0w   = (const float*)d_in[11];
  const float* wu0b   = (const float*)d_in[12];
  const float* wu1w   = (const float*)d_in[13];
  const float* wu1b   = (const float*)d_in[14];
  const float* wuw    = (const float*)d_in[15];
  const float* wub    = (const float*)d_in[16];
  const float* wh_w   = (const float*)d_in[17];
  const float* wh_b   = (const float*)d_in[18];
  const float* xst_w  = (const float*)d_in[19];
  const float* xst_b  = (const float*)d_in[20];
  const float* wrg_w  = (const float*)d_in[21];
  const float* wrs    = (const float*)d_in[22];
  const float* tWz    = (const float*)d_in[23];
  const float* tUzx   = (const float*)d_in[24];
  const float* tUzh   = (const float*)d_in[25];
  const float* tWr    = (const float*)d_in[26];
  const float* tUrx   = (const float*)d_in[27];
  const float* tUrh   = (const float*)d_in[28];
  const float* tWh    = (const float*)d_in[29];
  const float* tUhx   = (const float*)d_in[30];
  const float* tUhh   = (const float*)d_in[31];
  const float* tbz    = (const float*)d_in[32];
  const float* tbr    = (const float*)d_in[33];
  const float* tbh    = (const float*)d_in[34];

  float* ws = (float*)d_ws;
  unsigned* ctr = (unsigned*)(ws + CTR_OFF);

  hipMemsetAsync(ctr, 0, (TT + 1) * sizeof(unsigned), stream);
  gmgru_prep<<<(PREP_N + 255) / 256, 256, 0, stream>>>(
      data, gh_w, gh_b, gst_w, gst_b, wih, whh, wu0w, wu1w, wuw, ws);
  gmgru_main<<<NB, NT, 0, stream>>>(
      data, h0, H0, bih, bhh, wu0b, wu1b, wub, wh_w, wh_b, xst_w, xst_b,
      wrg_w, wrs, tWz, tUzx, tUzh, tWr, tUrx, tUrh, tWh, tUhx, tUhh, tbz, tbr,
      tbh, ws, ctr, (float*)d_out);
}